// Round 5
// baseline (3594.012 us; speedup 1.0000x reference)
//
#include <hip/hip_runtime.h>

// ---------------------------------------------------------------------------
// 2-layer GRU, B=64 S=2048 IN=208 H=100 OUT=98, fp32.
//   gemm_bias:  xg0 = seq @ w_ih_l0^T + b_ih_l0          (full-GPU GEMM)
//   gru_fused:  128 persistent blocks (64 producer = layer0, 64 consumer).
// R5: LDS-pipe-bound model (ds_read_b128 ~12cyc/instr/CU). Restructure to
// minimize LDS instructions per step:
//   * 5 waves (320 thr), 2 rows/thread for dot1 AND dot2, all four
//     accumulators share ONE pass of 13 h4 LDS reads per wave.
//   * pair k-split (even lane k<48, odd k>=48); pair-sum via DPP quad_perm
//     swap (VALU, not LDS).
//   * wave w owns gates j in [20w,20w+20): pair p<20 holds rows (j, 100+j)
//     = (r_j, z_j) locally; n_j fetched with one bpermute from pairs 20..29.
//   * gate computed fully in-register -> hs[nxt][j]; hs double-buffered;
//     ONE barrier per step.
// LDS ops/wave/step: 13 reads + 2 bpermute + 1 write (~175cyc; x5 = ~880/CU)
// vs R4's ~3000. Ring/flag protocol identical to the verified R4.
// ---------------------------------------------------------------------------

#define GB_BM 64
#define GB_BN 64
#define GB_BK 16

__global__ __launch_bounds__(256)
void gemm_bias(const float* __restrict__ A, const float* __restrict__ W,
               const float* __restrict__ bias, float* __restrict__ C,
               int Sc, long a_bs, long a_ss, long c_bs, long c_ss,
               int N, int K)
{
    __shared__ float As[GB_BK][68];
    __shared__ float Bs[GB_BK][68];
    const int tid = threadIdx.x;
    const int m0 = blockIdx.x * GB_BM;
    const int n0 = blockIdx.y * GB_BN;

    const int lm = tid >> 2;
    const int lk = (tid & 3) << 2;
    const int row = m0 + lm;
    const float* arow = A + (long)(row / Sc) * a_bs + (long)(row % Sc) * a_ss;
    const int wrow = n0 + lm;
    const float* wrp = W + (long)wrow * K;
    const bool wv_ok = (wrow < N);

    const int tx = tid & 15;
    const int ty = tid >> 4;

    float acc[4][4] = {};

    for (int k0 = 0; k0 < K; k0 += GB_BK) {
        float4 av, bv;
        if (k0 + GB_BK <= K) {
            av = *(const float4*)(arow + k0 + lk);
            bv = wv_ok ? *(const float4*)(wrp + k0 + lk) : make_float4(0.f,0.f,0.f,0.f);
        } else {
            av = make_float4(0.f,0.f,0.f,0.f);
            bv = make_float4(0.f,0.f,0.f,0.f);
            const int kb = k0 + lk;
            if (kb + 0 < K) { av.x = arow[kb+0]; if (wv_ok) bv.x = wrp[kb+0]; }
            if (kb + 1 < K) { av.y = arow[kb+1]; if (wv_ok) bv.y = wrp[kb+1]; }
            if (kb + 2 < K) { av.z = arow[kb+2]; if (wv_ok) bv.z = wrp[kb+2]; }
            if (kb + 3 < K) { av.w = arow[kb+3]; if (wv_ok) bv.w = wrp[kb+3]; }
        }
        As[lk+0][lm] = av.x; As[lk+1][lm] = av.y; As[lk+2][lm] = av.z; As[lk+3][lm] = av.w;
        Bs[lk+0][lm] = bv.x; Bs[lk+1][lm] = bv.y; Bs[lk+2][lm] = bv.z; Bs[lk+3][lm] = bv.w;
        __syncthreads();
        #pragma unroll
        for (int kk = 0; kk < GB_BK; kk++) {
            float4 a  = *(const float4*)&As[kk][ty << 2];
            float4 bb = *(const float4*)&Bs[kk][tx << 2];
            float ar[4] = {a.x, a.y, a.z, a.w};
            float br[4] = {bb.x, bb.y, bb.z, bb.w};
            #pragma unroll
            for (int i = 0; i < 4; i++)
                #pragma unroll
                for (int j = 0; j < 4; j++)
                    acc[i][j] += ar[i] * br[j];
        }
        __syncthreads();
    }

    #pragma unroll
    for (int i = 0; i < 4; i++) {
        const int r = m0 + (ty << 2) + i;
        float* crow = C + (long)(r / Sc) * c_bs + (long)(r % Sc) * c_ss;
        #pragma unroll
        for (int j = 0; j < 4; j++) {
            const int col = n0 + (tx << 2) + j;
            if (col < N) crow[col] = acc[i][j] + bias[col];
        }
    }
}

// ---------------------------------------------------------------------------

#define RING_W 256   // ring depth in timesteps (power of 2), per batch
#define KPUB   16    // flag publish / wait granularity (power of 2)

__device__ __forceinline__ float fsig(float x)  { return 1.f / (1.f + __expf(-x)); }
__device__ __forceinline__ float ftanh(float x) { return 1.f - 2.f / (1.f + __expf(2.f * x)); }

__device__ __forceinline__ void bar_lgkm() {
    asm volatile("s_waitcnt lgkmcnt(0)" ::: "memory");
    __builtin_amdgcn_sched_barrier(0);
    __builtin_amdgcn_s_barrier();
}
__device__ __forceinline__ void bar_full() {
    asm volatile("s_waitcnt vmcnt(0) lgkmcnt(0)" ::: "memory");
    __builtin_amdgcn_sched_barrier(0);
    __builtin_amdgcn_s_barrier();
}
__device__ __forceinline__ void wait_ge(int* p, int tgt) {
    int spins = 0;
    while (__hip_atomic_load(p, __ATOMIC_ACQUIRE, __HIP_MEMORY_SCOPE_AGENT) < tgt) {
        __builtin_amdgcn_s_sleep(2);
        if (++spins > (1 << 22)) break;
    }
}
// pair-swap (lane 2k <-> 2k+1) via DPP quad_perm(1,0,3,2): pure VALU
__device__ __forceinline__ float dpp_swap1(float x) {
    int r = __builtin_amdgcn_update_dpp(0, __float_as_int(x), 0xB1, 0xF, 0xF, false);
    return __int_as_float(r);
}

__global__ __launch_bounds__(320, 2)
void gru_fused(const float* __restrict__ xg0,      // (B,S,300) precomputed
               const float* __restrict__ w_hh0, const float* __restrict__ b_hh0,
               const float* __restrict__ w_ih1, const float* __restrict__ b_ih1,
               const float* __restrict__ w_hh1, const float* __restrict__ b_hh1,
               const float* __restrict__ w_out, const float* __restrict__ b_out,
               const float* __restrict__ h_init, // (2,B,100)
               float* __restrict__ ring,          // (B, RING_W, 300)
               int* prog0, int* cons1,            // 64*32 ints each
               float* __restrict__ out,           // (B,S,98)
               int S)
{
    __shared__ __align__(16) float hs[2][104];    // double-buffered h state

    const int tid   = threadIdx.x;
    const int layer = blockIdx.x >> 6;   // 0 producer / 1 consumer
    const int b     = blockIdx.x & 63;

    const int wv    = tid >> 6;          // wave 0..4
    const int lane  = tid & 63;
    const int p     = lane >> 1;         // pair 0..31
    const int halfd = lane & 1;          // k-half: 0 -> k<48, 1 -> k>=48
    const int jw    = 20 * wv;
    const int pj    = (p < 20) ? p : 19;
    const int j     = jw + pj;           // gate index (valid when p<20), <=99
    const bool gate = (halfd == 0) && (p < 20);

    // dot1 rows: pairs 0..19 -> (r_j, z_j); pairs 20..29 -> (n_{2m}, n_{2m+1})
    int rA1, rB1;
    if (p < 20)      { rA1 = jw + p;              rB1 = 100 + jw + p; }
    else if (p < 30) { rA1 = 200 + jw + 2*(p-20); rB1 = rA1 + 1; }
    else             { rA1 = 0;                   rB1 = 1; }

    // dot2 rows: thread-pair e covers rows e and e+160
    const int e   = wv * 32 + p;                  // 0..159
    const int N2  = layer ? 98 : 300;
    const bool actA2 = (e < N2);
    const bool actB2 = (e + 160 < N2);
    const int r2A = actA2 ? e : 0;
    const int r2B = actB2 ? e + 160 : 0;

    int* myprog = prog0 + b * 32;
    int* mycons = cons1 + b * 32;

    const float* w_hh = layer ? w_hh1 : w_hh0;
    const float* W2   = layer ? w_out : w_ih1;
    const float* bhh  = layer ? b_hh1 : b_hh0;
    const float* b2   = layer ? b_out : b_ih1;

    // --- weights in registers: 4 rows x 13 float4 -------------------------
    float4 wA1[13], wB1[13], wA2[13], wB2[13];
    {
        const float* pa = w_hh + rA1 * 100 + halfd * 48;
        const float* pb = w_hh + rB1 * 100 + halfd * 48;
        const float* qa = W2   + r2A * 100 + halfd * 48;
        const float* qb = W2   + r2B * 100 + halfd * 48;
        #pragma unroll
        for (int i = 0; i < 13; i++) {
            wA1[i] = *(const float4*)(pa + 4 * i);
            wB1[i] = *(const float4*)(pb + 4 * i);
            wA2[i] = *(const float4*)(qa + 4 * i);
            wB2[i] = *(const float4*)(qb + 4 * i);
        }
        if (!halfd) {   // half0 covers k<48 only: zero the overlap f4
            wA1[12] = make_float4(0.f,0.f,0.f,0.f);
            wB1[12] = make_float4(0.f,0.f,0.f,0.f);
            wA2[12] = make_float4(0.f,0.f,0.f,0.f);
            wB2[12] = make_float4(0.f,0.f,0.f,0.f);
        }
    }
    const float bR = bhh[j], bZ = bhh[100 + j], bN = bhh[200 + j];
    const float b2A = b2[r2A], b2B = b2[r2B];

    float hcur = 0.f;
    if (gate) hcur = h_init[layer * 6400 + b * 100 + j];
    if (tid < 100) hs[0][tid] = h_init[layer * 6400 + b * 100 + tid];

    float* ringb     = ring + (size_t)b * RING_W * 300;
    const float* xgb = xg0 + (size_t)b * (size_t)S * 300;
    float* outb      = out + (size_t)b * (size_t)S * 98;

    float xRn = 0.f, xZn = 0.f, xNn = 0.f;   // prefetched gate x for next step

    if (layer == 0) {
        if (gate) {
            xRn = xgb[j]; xZn = xgb[100 + j]; xNn = xgb[200 + j];
        }
    } else {
        if (tid == 0) wait_ge(myprog, (S < KPUB + 1) ? S : (KPUB + 1));
    }
    __syncthreads();
    if (layer == 1 && gate) {
        xRn = ringb[j]; xZn = ringb[100 + j]; xNn = ringb[200 + j];
    }

    const int slb = 40 + (pj & ~1);      // bpermute source lane for n_j

    for (int t = 0; t < S; t++) {
        const int cur = t & 1;
        const int nxt = cur ^ 1;
        const float xR = xRn, xZ = xZn, xN = xNn;

        // prefetch x for step t+1 (loads stay in flight across the barrier)
        if (gate && t + 1 < S) {
            const float* src = (layer == 0)
                ? xgb + (size_t)(t + 1) * 300
                : ringb + (size_t)((t + 1) & (RING_W - 1)) * 300;
            xRn = src[j]; xZn = src[100 + j]; xNn = src[200 + j];
        }

        // ---- one pass over h_{t-1}: 13 LDS reads feed all 4 accumulators -
        const float4* h4p = (const float4*)hs[cur];
        const int base = halfd * 12;
        float a0[4] = {0.f,0.f,0.f,0.f}, a1[4] = {0.f,0.f,0.f,0.f};
        float a2[4] = {0.f,0.f,0.f,0.f}, a3[4] = {0.f,0.f,0.f,0.f};
        #pragma unroll
        for (int i = 0; i < 13; i++) {
            const float4 h4 = h4p[base + i];
            a0[0] += wA1[i].x * h4.x; a1[0] += wA1[i].y * h4.y;
            a2[0] += wA1[i].z * h4.z; a3[0] += wA1[i].w * h4.w;
            a0[1] += wB1[i].x * h4.x; a1[1] += wB1[i].y * h4.y;
            a2[1] += wB1[i].z * h4.z; a3[1] += wB1[i].w * h4.w;
            a0[2] += wA2[i].x * h4.x; a1[2] += wA2[i].y * h4.y;
            a2[2] += wA2[i].z * h4.z; a3[2] += wA2[i].w * h4.w;
            a0[3] += wB2[i].x * h4.x; a1[3] += wB2[i].y * h4.y;
            a2[3] += wB2[i].z * h4.z; a3[3] += wB2[i].w * h4.w;
        }
        float full[4];
        #pragma unroll
        for (int g = 0; g < 4; g++) {
            const float s = (a0[g] + a2[g]) + (a1[g] + a3[g]);
            full[g] = s + dpp_swap1(s);          // pair-sum: both lanes full
        }

        // n_j lives on pair 20+(j>>1), acc (j&1): one bpermute per acc
        const float nA = __shfl(full[0], slb);
        const float nB = __shfl(full[1], slb);

        if (gate) {
            const float dN = (pj & 1) ? nB : nA;
            const float r = fsig(xR + full[0] + bR);
            const float z = fsig(xZ + full[1] + bZ);
            const float n = ftanh(xN + r * (dN + bN));
            hcur = (1.f - z) * n + z * hcur;
            hs[nxt][j] = hcur;
        }

        // ---- dot2 result for h_{t-1} -> slot/row t-1 ---------------------
        if (t > 0 && halfd == 0) {
            if (layer == 0) {
                float* dst = ringb + (size_t)((t - 1) & (RING_W - 1)) * 300;
                if (actA2) dst[r2A] = full[2] + b2A;
                if (actB2) dst[r2B] = full[3] + b2B;
            } else {
                if (actA2) outb[(size_t)(t - 1) * 98 + r2A] = full[2] + b2A;
            }
        }

        // ---- single barrier + flag protocol ------------------------------
        if (((t + 1) & (KPUB - 1)) == 0) {
            if (layer == 0) {
                bar_full();   // drains ring stores of slots <= t-1
                if (tid == 0) {
                    __hip_atomic_store(myprog, t, __ATOMIC_RELEASE, __HIP_MEMORY_SCOPE_AGENT);
                    const int need = t - 240;         // ring back-pressure
                    if (need > 0) wait_ge(mycons, need);
                }
            } else {
                if (tid == 0) {
                    __hip_atomic_store(mycons, t, __ATOMIC_RELEASE, __HIP_MEMORY_SCOPE_AGENT);
                    int tgt = t + 2 + KPUB;           // covers prefetch <= slot t+1+KPUB
                    if (tgt > S) tgt = S;
                    wait_ge(myprog, tgt);             // BEFORE barrier
                }
                bar_lgkm();
            }
        } else {
            bar_lgkm();
        }
    }

    // ---- final dot2 for h_{S-1} (in hs[S&1]) -----------------------------
    {
        const float4* h4p = (const float4*)hs[S & 1];
        const int base = halfd * 12;
        float c0A = 0.f, c1A = 0.f, c2A = 0.f, c3A = 0.f;
        float c0B = 0.f, c1B = 0.f, c2B = 0.f, c3B = 0.f;
        #pragma unroll
        for (int i = 0; i < 13; i++) {
            const float4 h4 = h4p[base + i];
            c0A += wA2[i].x * h4.x; c1A += wA2[i].y * h4.y;
            c2A += wA2[i].z * h4.z; c3A += wA2[i].w * h4.w;
            c0B += wB2[i].x * h4.x; c1B += wB2[i].y * h4.y;
            c2B += wB2[i].z * h4.z; c3B += wB2[i].w * h4.w;
        }
        float sA = (c0A + c2A) + (c1A + c3A); sA += dpp_swap1(sA);
        float sB = (c0B + c2B) + (c1B + c3B); sB += dpp_swap1(sB);
        if (halfd == 0) {
            if (layer == 0) {
                float* dst = ringb + (size_t)((S - 1) & (RING_W - 1)) * 300;
                if (actA2) dst[r2A] = sA + b2A;
                if (actB2) dst[r2B] = sB + b2B;
            } else {
                if (actA2) outb[(size_t)(S - 1) * 98 + r2A] = sA + b2A;
            }
        }
    }
    if (layer == 0) {
        bar_full();          // drain slot S-1
        if (tid == 0)
            __hip_atomic_store(myprog, S, __ATOMIC_RELEASE, __HIP_MEMORY_SCOPE_AGENT);
    }
}

// ---------------------------------------------------------------------------

extern "C" void kernel_launch(void* const* d_in, const int* in_sizes, int n_in,
                              void* d_out, int out_size, void* d_ws, size_t ws_size,
                              hipStream_t stream)
{
    const float* seq    = (const float*)d_in[0];
    const float* h0     = (const float*)d_in[1];   // (2, 64, 100)
    const float* w_ih0  = (const float*)d_in[2];   // (300, 208)
    const float* w_hh0  = (const float*)d_in[3];   // (300, 100)
    const float* b_ih0  = (const float*)d_in[4];
    const float* b_hh0  = (const float*)d_in[5];
    const float* w_ih1  = (const float*)d_in[6];   // (300, 100)
    const float* w_hh1  = (const float*)d_in[7];
    const float* b_ih1  = (const float*)d_in[8];
    const float* b_hh1  = (const float*)d_in[9];
    const float* w_out  = (const float*)d_in[10];  // (98, 100)
    const float* b_out  = (const float*)d_in[11];
    float* out = (float*)d_out;

    const int B = 64, S = 2048, IN = 208, G = 300;

    // workspace: flags (2 * 64*32 ints) | xg0 (B,S,300) | ring (B,RING_W,300)
    int* prog0 = (int*)d_ws;
    int* cons1 = prog0 + 64 * 32;
    float* xg0 = (float*)(cons1 + 64 * 32);
    float* ringbuf = xg0 + (size_t)B * S * G;

    hipMemsetAsync(d_ws, 0, 2 * 64 * 32 * sizeof(int), stream);

    // xg0 = seq @ w_ih0^T + b_ih0   (full S in one pass)
    const dim3 blk(256);
    const dim3 gX((B * S) / GB_BM, (G + GB_BN - 1) / GB_BN);   // (2048, 5)
    gemm_bias<<<gX, blk, 0, stream>>>(seq, w_ih0, b_ih0, xg0,
                                      S, (long)S * IN, (long)IN,
                                      (long)S * G, (long)G, G, IN);

    // fused persistent 2-layer scan + projections
    gru_fused<<<dim3(128), dim3(320), 0, stream>>>(
        xg0, w_hh0, b_hh0, w_ih1, b_ih1, w_hh1, b_hh1, w_out, b_out,
        h0, ringbuf, prog0, cons1, out, S);
}

// Round 6
// 2464.500 us; speedup vs baseline: 1.4583x; 1.4583x over previous
//
#include <hip/hip_runtime.h>

// ---------------------------------------------------------------------------
// 2-layer GRU, B=64 S=2048 IN=208 H=100 OUT=98, fp32.
//   gemm_bias:  xg0 = seq @ w_ih_l0^T + b_ih_l0          (full-GPU GEMM)
//   gru_fused:  128 persistent blocks (64 producer = layer0, 64 consumer).
// R6 = R3's verified structure with ONE change: single h-pass per step.
// Thread pair g (2-way k-split) computes BOTH dot1 (w_hh row g) and dot2
// (w_ih1/w_out row g) from the same 13 ds_read_b128 of h_{t-1}. dot2 result
// goes to ring/out slot t-1 (one-step lag; epilogue emits slot S-1).
// LDS instrs/step: ~130+gate vs R3's ~260+gate -> model predicts ~0.55x step.
// Weights: 26 float4/thread (AGPR-safe size, proven R0/R1). Protocol = R3.
// ---------------------------------------------------------------------------

#define GB_BM 64
#define GB_BN 64
#define GB_BK 16

__global__ __launch_bounds__(256)
void gemm_bias(const float* __restrict__ A, const float* __restrict__ W,
               const float* __restrict__ bias, float* __restrict__ C,
               int Sc, long a_bs, long a_ss, long c_bs, long c_ss,
               int N, int K)
{
    __shared__ float As[GB_BK][68];
    __shared__ float Bs[GB_BK][68];
    const int tid = threadIdx.x;
    const int m0 = blockIdx.x * GB_BM;
    const int n0 = blockIdx.y * GB_BN;

    const int lm = tid >> 2;
    const int lk = (tid & 3) << 2;
    const int row = m0 + lm;
    const float* arow = A + (long)(row / Sc) * a_bs + (long)(row % Sc) * a_ss;
    const int wrow = n0 + lm;
    const float* wrp = W + (long)wrow * K;
    const bool wv_ok = (wrow < N);

    const int tx = tid & 15;
    const int ty = tid >> 4;

    float acc[4][4] = {};

    for (int k0 = 0; k0 < K; k0 += GB_BK) {
        float4 av, bv;
        if (k0 + GB_BK <= K) {
            av = *(const float4*)(arow + k0 + lk);
            bv = wv_ok ? *(const float4*)(wrp + k0 + lk) : make_float4(0.f,0.f,0.f,0.f);
        } else {
            av = make_float4(0.f,0.f,0.f,0.f);
            bv = make_float4(0.f,0.f,0.f,0.f);
            const int kb = k0 + lk;
            if (kb + 0 < K) { av.x = arow[kb+0]; if (wv_ok) bv.x = wrp[kb+0]; }
            if (kb + 1 < K) { av.y = arow[kb+1]; if (wv_ok) bv.y = wrp[kb+1]; }
            if (kb + 2 < K) { av.z = arow[kb+2]; if (wv_ok) bv.z = wrp[kb+2]; }
            if (kb + 3 < K) { av.w = arow[kb+3]; if (wv_ok) bv.w = wrp[kb+3]; }
        }
        As[lk+0][lm] = av.x; As[lk+1][lm] = av.y; As[lk+2][lm] = av.z; As[lk+3][lm] = av.w;
        Bs[lk+0][lm] = bv.x; Bs[lk+1][lm] = bv.y; Bs[lk+2][lm] = bv.z; Bs[lk+3][lm] = bv.w;
        __syncthreads();
        #pragma unroll
        for (int kk = 0; kk < GB_BK; kk++) {
            float4 a  = *(const float4*)&As[kk][ty << 2];
            float4 bb = *(const float4*)&Bs[kk][tx << 2];
            float ar[4] = {a.x, a.y, a.z, a.w};
            float br[4] = {bb.x, bb.y, bb.z, bb.w};
            #pragma unroll
            for (int i = 0; i < 4; i++)
                #pragma unroll
                for (int j = 0; j < 4; j++)
                    acc[i][j] += ar[i] * br[j];
        }
        __syncthreads();
    }

    #pragma unroll
    for (int i = 0; i < 4; i++) {
        const int r = m0 + (ty << 2) + i;
        float* crow = C + (long)(r / Sc) * c_bs + (long)(r % Sc) * c_ss;
        #pragma unroll
        for (int j = 0; j < 4; j++) {
            const int col = n0 + (tx << 2) + j;
            if (col < N) crow[col] = acc[i][j] + bias[col];
        }
    }
}

// ---------------------------------------------------------------------------

#define RING_W 256   // ring depth in timesteps (power of 2), per batch
#define KPUB   16    // flag publish / wait granularity (power of 2)

__device__ __forceinline__ float fsig(float x)  { return 1.f / (1.f + __expf(-x)); }
__device__ __forceinline__ float ftanh(float x) { return 1.f - 2.f / (1.f + __expf(2.f * x)); }

__device__ __forceinline__ void bar_lgkm() {
    asm volatile("s_waitcnt lgkmcnt(0)" ::: "memory");
    __builtin_amdgcn_sched_barrier(0);
    __builtin_amdgcn_s_barrier();
}
__device__ __forceinline__ void bar_full() {
    asm volatile("s_waitcnt vmcnt(0) lgkmcnt(0)" ::: "memory");
    __builtin_amdgcn_sched_barrier(0);
    __builtin_amdgcn_s_barrier();
}
// Bounded spin: a protocol bug shows as a wrong result, not a dead container.
__device__ __forceinline__ void wait_ge(int* p, int tgt) {
    int spins = 0;
    while (__hip_atomic_load(p, __ATOMIC_ACQUIRE, __HIP_MEMORY_SCOPE_AGENT) < tgt) {
        __builtin_amdgcn_s_sleep(2);
        if (++spins > (1 << 22)) break;
    }
}

__global__ __launch_bounds__(640, 1)
void gru_fused(const float* __restrict__ xg0,      // (B,S,300) precomputed
               const float* __restrict__ w_hh0, const float* __restrict__ b_hh0,
               const float* __restrict__ w_ih1, const float* __restrict__ b_ih1,
               const float* __restrict__ w_hh1, const float* __restrict__ b_hh1,
               const float* __restrict__ w_out, const float* __restrict__ b_out,
               const float* __restrict__ h_init, // (2,B,100)
               float* __restrict__ ring,          // (B, RING_W, 300)
               int* prog0, int* cons1,            // 64*32 ints each
               float* __restrict__ out,           // (B,S,98)
               int S)
{
    __shared__ __align__(16) float hs[104];
    __shared__ float hg_lds[300];
    __shared__ float xg_lds[300];

    const int tid   = threadIdx.x;
    const int layer = blockIdx.x >> 6;   // 0 producer / 1 consumer
    const int b     = blockIdx.x & 63;
    const int half  = tid & 1;
    const int g     = tid >> 1;          // row index 0..319
    const bool dot  = (tid < 600);
    const bool even = dot && (half == 0);

    const int n2    = layer ? 98 : 300;  // dot2 row count
    const bool has2 = dot && (g < n2);
    const int g2c   = (dot && g < n2) ? g : 0;

    int* myprog = prog0 + b * 32;
    int* mycons = cons1 + b * 32;

    const float* w_hh = layer ? w_hh1 : w_hh0;
    const float* W2   = layer ? w_out : w_ih1;

    // --- weights in registers/AGPRs: 26 float4 per dot thread -------------
    float4 wv[13], wv2[13];
    float bhh = 0.f, bias2 = 0.f;
    if (dot) {
        const float* p = w_hh + g * 100 + half * 48;   // 16B aligned
        const float* q = W2 + g2c * 100 + half * 48;
        #pragma unroll
        for (int i = 0; i < 13; i++) {
            wv[i]  = *(const float4*)(p + 4 * i);
            wv2[i] = *(const float4*)(q + 4 * i);
        }
        if (!half) {                      // half0 covers k<48 only
            wv[12]  = make_float4(0.f, 0.f, 0.f, 0.f);
            wv2[12] = make_float4(0.f, 0.f, 0.f, 0.f);
        }
    }
    if (even) bhh = (layer ? b_hh1 : b_hh0)[g];
    if (even) bias2 = (layer ? b_out : b_ih1)[g2c];

    float hcur = 0.f;
    if (tid < 100) {
        hcur = h_init[layer * 6400 + b * 100 + tid];
        hs[tid] = hcur;
    }

    float* ringb     = ring + (size_t)b * RING_W * 300;
    const float* xgb = xg0 + (size_t)b * (size_t)S * 300;
    float* outb      = out + (size_t)b * (size_t)S * 98;

    float xnext = 0.f;

    if (layer == 0) {
        if (even) xnext = xgb[g];                       // prefetch t=0
    } else {
        if (tid == 0) wait_ge(myprog, (S < KPUB + 1) ? S : (KPUB + 1));
    }
    __syncthreads();
    if (layer == 1 && even) xnext = ringb[g];           // prefetch t=0

    for (int t = 0; t < S; t++) {
        const float xcur = xnext;
        // prefetch x for step t+1 (stays in flight across barriers)
        if (even && t + 1 < S) {
            xnext = (layer == 0)
                ? xgb[(size_t)(t + 1) * 300 + g]
                : ringb[(size_t)((t + 1) & (RING_W - 1)) * 300 + g];
        }

        // ---- single pass over h_{t-1}: 13 LDS reads feed BOTH dots -------
        float tot = 0.f, tot2 = 0.f;
        if (dot) {
            const float4* hs4 = (const float4*)hs;
            const int base = half * 12;
            float a0 = 0.f, a1 = 0.f, a2 = 0.f, a3 = 0.f;
            float c0 = 0.f, c1 = 0.f, c2 = 0.f, c3 = 0.f;
            #pragma unroll
            for (int i = 0; i < 13; i++) {
                const float4 h4 = hs4[base + i];
                const float4 w = wv[i];
                const float4 u = wv2[i];
                a0 += w.x * h4.x; a1 += w.y * h4.y;
                a2 += w.z * h4.z; a3 += w.w * h4.w;
                c0 += u.x * h4.x; c1 += u.y * h4.y;
                c2 += u.z * h4.z; c3 += u.w * h4.w;
            }
            tot = (a0 + a2) + (a1 + a3);
            tot += __shfl_down(tot, 1);          // even lane: full dot1
            tot2 = (c0 + c2) + (c1 + c3);
            tot2 += __shfl_down(tot2, 1);        // even lane: full dot2
        }
        if (even) { hg_lds[g] = tot + bhh; xg_lds[g] = xcur; }

        // dot2(h_{t-1}) -> ring/out slot t-1 (store stays in flight)
        if (even && has2 && t > 0) {
            if (layer == 0)
                ringb[(size_t)((t - 1) & (RING_W - 1)) * 300 + g] = tot2 + bias2;
            else
                outb[(size_t)(t - 1) * 98 + g] = tot2 + bias2;
        }

        // ---- sync1 + flag protocol (identical to verified R3) ------------
        if (layer == 0) {
            // publish steps need ring stores of slots <= t-1 drained first
            if ((t & (KPUB - 1)) == 0) bar_full(); else bar_lgkm();
            if (tid == 0 && t > 0 && (t & (KPUB - 1)) == 0) {
                __hip_atomic_store(myprog, t, __ATOMIC_RELEASE, __HIP_MEMORY_SCOPE_AGENT);
                const int need = t + KPUB - RING_W;   // ring back-pressure
                if (need > 0) wait_ge(mycons, need);
            }
        } else {
            bar_lgkm();
            if (tid == 0) {
                if (t > 0 && (t & (KPUB - 1)) == 0)
                    __hip_atomic_store(mycons, t, __ATOMIC_RELEASE, __HIP_MEMORY_SCOPE_AGENT);
                if (((t + 1) & (KPUB - 1)) == 0) {
                    int tgt = t + 2 + KPUB;           // covers next window's prefetches
                    if (tgt > S) tgt = S;
                    wait_ge(myprog, tgt);
                }
            }
        }

        // ---- gate phase --------------------------------------------------
        if (tid < 100) {
            const float xr = xg_lds[tid], xz = xg_lds[100 + tid], xn = xg_lds[200 + tid];
            const float hr = hg_lds[tid], hz = hg_lds[100 + tid], hn = hg_lds[200 + tid];
            const float r = fsig(xr + hr);
            const float z = fsig(xz + hz);
            const float n = ftanh(xn + r * hn);
            hcur = (1.f - z) * n + z * hcur;
            hs[tid] = hcur;
        }
        bar_lgkm();   // sync2 -- hs now holds h_t
    }

    // ---- epilogue: dot2 for h_{S-1} -> slot/row S-1 ----------------------
    if (dot) {
        const float4* hs4 = (const float4*)hs;
        const int base = half * 12;
        float c0 = 0.f, c1 = 0.f, c2 = 0.f, c3 = 0.f;
        #pragma unroll
        for (int i = 0; i < 13; i++) {
            const float4 h4 = hs4[base + i];
            const float4 u = wv2[i];
            c0 += u.x * h4.x; c1 += u.y * h4.y;
            c2 += u.z * h4.z; c3 += u.w * h4.w;
        }
        float tot2 = (c0 + c2) + (c1 + c3);
        tot2 += __shfl_down(tot2, 1);
        if (even && has2) {
            if (layer == 0)
                ringb[(size_t)((S - 1) & (RING_W - 1)) * 300 + g] = tot2 + bias2;
            else
                outb[(size_t)(S - 1) * 98 + g] = tot2 + bias2;
        }
    }
    if (layer == 0) {
        bar_full();          // drain slot S-1
        if (tid == 0)
            __hip_atomic_store(myprog, S, __ATOMIC_RELEASE, __HIP_MEMORY_SCOPE_AGENT);
    }
}

// ---------------------------------------------------------------------------

extern "C" void kernel_launch(void* const* d_in, const int* in_sizes, int n_in,
                              void* d_out, int out_size, void* d_ws, size_t ws_size,
                              hipStream_t stream)
{
    const float* seq    = (const float*)d_in[0];
    const float* h0     = (const float*)d_in[1];   // (2, 64, 100)
    const float* w_ih0  = (const float*)d_in[2];   // (300, 208)
    const float* w_hh0  = (const float*)d_in[3];   // (300, 100)
    const float* b_ih0  = (const float*)d_in[4];
    const float* b_hh0  = (const float*)d_in[5];
    const float* w_ih1  = (const float*)d_in[6];   // (300, 100)
    const float* w_hh1  = (const float*)d_in[7];
    const float* b_ih1  = (const float*)d_in[8];
    const float* b_hh1  = (const float*)d_in[9];
    const float* w_out  = (const float*)d_in[10];  // (98, 100)
    const float* b_out  = (const float*)d_in[11];
    float* out = (float*)d_out;

    const int B = 64, S = 2048, IN = 208, G = 300;

    // workspace: flags (2 * 64*32 ints) | xg0 (B,S,300) | ring (B,RING_W,300)
    int* prog0 = (int*)d_ws;
    int* cons1 = prog0 + 64 * 32;
    float* xg0 = (float*)(cons1 + 64 * 32);
    float* ringbuf = xg0 + (size_t)B * S * G;

    hipMemsetAsync(d_ws, 0, 2 * 64 * 32 * sizeof(int), stream);

    // xg0 = seq @ w_ih0^T + b_ih0   (full S in one pass)
    const dim3 blk(256);
    const dim3 gX((B * S) / GB_BM, (G + GB_BN - 1) / GB_BN);   // (2048, 5)
    gemm_bias<<<gX, blk, 0, stream>>>(seq, w_ih0, b_ih0, xg0,
                                      S, (long)S * IN, (long)IN,
                                      (long)S * G, (long)G, G, IN);

    // fused persistent 2-layer scan + projections
    gru_fused<<<dim3(128), dim3(640), 0, stream>>>(
        xg0, w_hh0, b_hh0, w_ih1, b_ih1, w_hh1, b_hh1, w_out, b_out,
        h0, ringbuf, prog0, cons1, out, S);
}